// Round 16
// baseline (138.122 us; speedup 1.0000x reference)
//
#include <hip/hip_runtime.h>

#define DD 512
#define KM 5
#define B_ROWS 32768

typedef __attribute__((ext_vector_type(8))) short short8;
typedef __attribute__((ext_vector_type(4))) short s16x4;
typedef __attribute__((ext_vector_type(4))) float f32x4;

static __device__ __forceinline__ short f2bf(float x) {
  unsigned u = __builtin_bit_cast(unsigned, x);
  u = (u + 0x7fffu + ((u >> 16) & 1u)) >> 16;
  return (short)u;
}
static __device__ __forceinline__ float bf2f(short s) {
  unsigned u = ((unsigned)(unsigned short)s) << 16;
  return __builtin_bit_cast(float, u);
}

// lgkm-only barrier: LDS ordered; global loads stay in flight
#define BAR_LGKM() do { asm volatile("s_waitcnt lgkmcnt(0)" ::: "memory"); __builtin_amdgcn_s_barrier(); } while (0)

// ---------------- prepG: At/Ct via MFMA (64 blocks, PACKED output) + w0 + d0 ----------------
// Packed layout: P[ki][j][kk] (ki = col>>5, kk = col&31) — wave B-frag = contiguous 1 KB.
__global__ __launch_bounds__(512, 2)
void prepG(const float* __restrict__ Wq, const float* __restrict__ bq,
           const float* __restrict__ Wk, const float* __restrict__ Wv,
           const float* __restrict__ Wo, const float* __restrict__ bo,
           const float* __restrict__ bv,
           short* __restrict__ At, short* __restrict__ Ct,
           float* __restrict__ w0, float* __restrict__ d0) {
  __shared__ short sh[12288];          // 24 KB: As dbuf 2x8KB + Bs dbuf 2x4KB
  const int tid = threadIdx.x;
  const int blk = blockIdx.x;
  if (blk < 64) {
    const bool isC = blk >= 32;
    const int b = blk & 31;
    const int j0 = (b >> 3) * 128;     // M tile (output rows j)
    const int i0 = (b & 7) * 64;       // N tile (output cols i)
    const int lane = tid & 63;
    const int w = tid >> 6;
    const int wm = w & 1, wn = w >> 1; // wave grid 2M x 4N
    const int kg = lane >> 4, lr = lane & 15;
    const float* Ysrc = isC ? Wv : Wq;
    f32x4 acc[4] = {};
    f32x4 ra0, ra1;
    f32x4 rbv;
    if (!isC) {
      const float* p = Wk + (size_t)(j0 + (tid >> 2)) * DD + (tid & 3) * 8;
      ra0 = *(const f32x4*)p; ra1 = *(const f32x4*)(p + 4);
    } else {
      const float* p = Wo + (size_t)(tid >> 4) * DD + j0 + (tid & 15) * 8;
      ra0 = *(const f32x4*)p; ra1 = *(const f32x4*)(p + 4);
    }
    rbv = *(const f32x4*)(Ysrc + (size_t)(i0 + (tid >> 3)) * DD + (tid & 7) * 4);
    for (int ki = 0; ki < 16; ++ki) {
      short* As = (ki & 1) ? (sh + 4096) : sh;             // [128][32]
      short* Bs = (ki & 1) ? (sh + 10240) : (sh + 8192);   // [64][32]
      if (!isC) {
        short8 sv;
        sv[0]=f2bf(ra0[0]); sv[1]=f2bf(ra0[1]); sv[2]=f2bf(ra0[2]); sv[3]=f2bf(ra0[3]);
        sv[4]=f2bf(ra1[0]); sv[5]=f2bf(ra1[1]); sv[6]=f2bf(ra1[2]); sv[7]=f2bf(ra1[3]);
        *(short8*)&As[(tid >> 2) * 32 + (((tid & 3) * 8) ^ (((tid >> 2) & 3) << 3))] = sv;
      } else {
        const int e = tid >> 4;
#pragma unroll
        for (int c = 0; c < 8; ++c) {
          const int j = (tid & 15) * 8 + c;
          const float v = (c < 4) ? ra0[c & 3] : ra1[c & 3];
          As[j * 32 + (e ^ ((j & 3) << 3))] = f2bf(v);
        }
      }
      {
        s16x4 sv;
        sv[0]=f2bf(rbv[0]); sv[1]=f2bf(rbv[1]); sv[2]=f2bf(rbv[2]); sv[3]=f2bf(rbv[3]);
        *(s16x4*)&Bs[(tid >> 3) * 32 + (((tid & 7) * 4) ^ (((tid >> 3) & 3) << 3))] = sv;
      }
      if (ki < 15) {
        const int kt = (ki + 1) * 32;
        if (!isC) {
          const float* p = Wk + (size_t)(j0 + (tid >> 2)) * DD + kt + (tid & 3) * 8;
          ra0 = *(const f32x4*)p; ra1 = *(const f32x4*)(p + 4);
        } else {
          const float* p = Wo + (size_t)(kt + (tid >> 4)) * DD + j0 + (tid & 15) * 8;
          ra0 = *(const f32x4*)p; ra1 = *(const f32x4*)(p + 4);
        }
        rbv = *(const f32x4*)(Ysrc + (size_t)(i0 + (tid >> 3)) * DD + kt + (tid & 7) * 4);
      }
      __syncthreads();
      short8 av[4], bvv;
#pragma unroll
      for (int mi = 0; mi < 4; ++mi) {
        const int ar = wm * 64 + mi * 16 + lr;
        av[mi] = *(const short8*)&As[ar * 32 + ((kg * 8) ^ ((lr & 3) << 3))];
      }
      {
        const int br = wn * 16 + lr;
        bvv = *(const short8*)&Bs[br * 32 + ((kg * 8) ^ ((lr & 3) << 3))];
      }
#pragma unroll
      for (int mi = 0; mi < 4; ++mi)
        acc[mi] = __builtin_amdgcn_mfma_f32_16x16x32_bf16(av[mi], bvv, acc[mi], 0, 0, 0);
      __syncthreads();
    }
    short* P = isC ? Ct : At;
    const int cwl = wn * 16 + lr;
    const int kiv = (b & 7) * 2 + (cwl >> 5);
    const int kkv = cwl & 31;
#pragma unroll
    for (int mi = 0; mi < 4; ++mi)
#pragma unroll
      for (int r = 0; r < 4; ++r) {
        const int j = j0 + wm * 64 + mi * 16 + kg * 4 + r;
        P[(size_t)kiv * 16384 + j * 32 + kkv] = f2bf(acc[mi][r]);
      }
  } else if (blk < 128) {
    const int j = (blk - 64) * 8 + (tid >> 6);
    const int lane = tid & 63;
    const float* r = Wk + (size_t)j * DD + lane * 8;
    f32x4 a = *(const f32x4*)r;
    f32x4 c = *(const f32x4*)(r + 4);
    const float* bp = bq + lane * 8;
    f32x4 ba = *(const f32x4*)bp;
    f32x4 bc = *(const f32x4*)(bp + 4);
    float s = a[0]*ba[0] + a[1]*ba[1] + a[2]*ba[2] + a[3]*ba[3]
            + c[0]*bc[0] + c[1]*bc[1] + c[2]*bc[2] + c[3]*bc[3];
#pragma unroll
    for (int off = 32; off > 0; off >>= 1) s += __shfl_xor(s, off);
    if (lane == 0) w0[j] = s;
  } else {
    float* red = (float*)sh;     // [2][256]
    const int j = (blk - 128) * 256 + (tid & 255);
    const int half = tid >> 8;
    float s = 0.f;
    for (int e = half * 256; e < half * 256 + 256; ++e)
      s += bv[e] * Wo[(size_t)e * DD + j];
    red[half * 256 + (tid & 255)] = s;
    __syncthreads();
    if (half == 0) d0[j] = red[tid] + red[256 + tid] + bo[j];
  }
}

// write one 128x32 A k-slice row-chunk (8 bf16) from two f32x4
#define WRITE_A(DST, QLO, QHI) do {                                                \
  short8 _sv;                                                                      \
  _sv[0]=f2bf((QLO)[0]); _sv[1]=f2bf((QLO)[1]); _sv[2]=f2bf((QLO)[2]); _sv[3]=f2bf((QLO)[3]); \
  _sv[4]=f2bf((QHI)[0]); _sv[5]=f2bf((QHI)[1]); _sv[6]=f2bf((QHI)[2]); _sv[7]=f2bf((QHI)[3]); \
  *(short8*)&(DST)[arow * 32 + (acol ^ ((arow & 3) << 3))] = _sv; } while (0)

// GEMM1 iter: A frags (LDS ping-pong), B frags prefetched from packed global, q reg ping
#define G1ITER(KI, ASC, ASN, BC, BN) do {                                   \
    short8 av[8];                                                           \
    _Pragma("unroll") for (int mi = 0; mi < 8; ++mi) {                      \
      const int ar = mi * 16 + lr;                                          \
      av[mi] = *(const short8*)&(ASC)[ar * 32 + ((kg * 8) ^ ((lr & 3) << 3))]; \
    }                                                                       \
    if ((KI) < 15) { WRITE_A(ASN, qA, qB); }                                \
    if ((KI) < 15) {                                                        \
      _Pragma("unroll") for (int ni = 0; ni < 4; ++ni)                      \
        (BN)[ni] = *(const short8*)(atb + ((KI) + 1) * 16384 + ni * 512);   \
    }                                                                       \
    if ((KI) < 14) {                                                        \
      qA = *(const f32x4*)(qbase + ((KI) + 2) * 32);                        \
      qB = *(const f32x4*)(qbase + ((KI) + 2) * 32 + 4);                    \
    }                                                                       \
    _Pragma("unroll") for (int mi = 0; mi < 8; ++mi)                        \
      _Pragma("unroll") for (int ni = 0; ni < 4; ++ni)                      \
        acc[mi][ni] = __builtin_amdgcn_mfma_f32_16x16x32_bf16(av[mi], (BC)[ni], acc[mi][ni], 0, 0, 0); \
    BAR_LGKM();                                                             \
  } while (0)

// GEMM2 iter: A from R1 (swizzled, read-only), B prefetch from global — NO barriers
#define G2ITER(KI, BC, BN) do {                                             \
    short8 av[8];                                                           \
    _Pragma("unroll") for (int mi = 0; mi < 8; ++mi) {                      \
      const int ar = mi * 16 + lr;                                          \
      av[mi] = *(const short8*)&R1[(ar * DD + (KI) * 32 + kg * 8) ^ ((ar & 7) << 3)]; \
    }                                                                       \
    if ((KI) < 15) {                                                        \
      _Pragma("unroll") for (int ni = 0; ni < 4; ++ni)                      \
        (BN)[ni] = *(const short8*)(ctb + ((KI) + 1) * 16384 + ni * 512);   \
    }                                                                       \
    _Pragma("unroll") for (int mi = 0; mi < 8; ++mi)                        \
      _Pragma("unroll") for (int ni = 0; ni < 4; ++ni)                      \
        acc2[mi][ni] = __builtin_amdgcn_mfma_f32_16x16x32_bf16(av[mi], (BC)[ni], acc2[mi][ni], 0, 0, 0); \
  } while (0)

// softmax+weighted-sum finisher; writes mbar row into R1 with (row&7)<<3 swizzle
#define ROW_FINISH(SV, MA, MC, VM, ROW)                                     \
    {                                                                       \
      float mx = -1e30f;                                                    \
      _Pragma("unroll") for (int k = 0; k < KM; ++k)                        \
        if ((VM) & (1 << k)) mx = fmaxf(mx, SV[k]);                         \
      float wk[KM]; float sum = 0.f;                                        \
      _Pragma("unroll") for (int k = 0; k < KM; ++k) {                      \
        wk[k] = ((VM) & (1 << k)) ? __expf(SV[k] - mx) : 0.f;               \
        sum += wk[k];                                                       \
      }                                                                     \
      const float inv = 1.f / sum;                                          \
      float o[8] = {0.f,0.f,0.f,0.f,0.f,0.f,0.f,0.f};                       \
      _Pragma("unroll") for (int k = 0; k < KM; ++k)                        \
        if ((VM) & (1 << k)) {                                              \
          const float g = wk[k] * inv;                                      \
          _Pragma("unroll") for (int i = 0; i < 4; ++i) {                   \
            o[i] += g * MA[k][i]; o[4 + i] += g * MC[k][i];                 \
          }                                                                 \
        }                                                                   \
      short8 ov;                                                            \
      _Pragma("unroll") for (int i = 0; i < 8; ++i) ov[i] = f2bf(o[i]);     \
      *(short8*)&R1[((ROW) * DD + lane * 8) ^ (((ROW) & 7) << 3)] = ov;     \
    }

// Fused megakernel, 128 rows/block, 8 waves, grid 256.
// LDS = R1 128 KB (As ping-pong 2x8KB aliased at head during GEMM1; t -> mbar(swz) -> memO).
__global__ __launch_bounds__(512, 2)
void mk(const float* __restrict__ q, const short* __restrict__ AtP,
        const float* __restrict__ w0, const float* __restrict__ mem,
        const int* __restrict__ mask, const short* __restrict__ CtP,
        const float* __restrict__ d0, const float* __restrict__ sims,
        const float* __restrict__ Wg, const float* __restrict__ bgp,
        const float* __restrict__ lng, const float* __restrict__ lnb,
        float* __restrict__ outp) {
  __shared__ short R1[128 * DD];     // 128 KB
  const int tid = threadIdx.x;
  const int lane = tid & 63;
  const int w = tid >> 6;
  const int kg = lane >> 4, lr = lane & 15;
  const int bm = blockIdx.x;

  short* As0 = R1;                   // [128][32] 8 KB
  short* As1 = R1 + 4096;            // 8 KB

  const short* atb = AtP + (size_t)(w * 64 + lr) * 32 + kg * 8;
  const short* ctb = CtP + (size_t)(w * 64 + lr) * 32 + kg * 8;

  // ---------- phase 0: GEMM1  t = q @ A ----------
  f32x4 acc[8][4] = {};
  const int arow = tid >> 2, acol = (tid & 3) * 8;
  const float* qbase = q + (size_t)(bm * 128 + arow) * DD + acol;
  {
    f32x4 qA = *(const f32x4*)qbase;
    f32x4 qB = *(const f32x4*)(qbase + 4);
    WRITE_A(As0, qA, qB);
    qA = *(const f32x4*)(qbase + 32);
    qB = *(const f32x4*)(qbase + 36);
    short8 bA[4], bB[4];
#pragma unroll
    for (int ni = 0; ni < 4; ++ni) bA[ni] = *(const short8*)(atb + ni * 512);
    BAR_LGKM();
    for (int kp = 0; kp < 8; ++kp) {
      G1ITER(2 * kp,     As0, As1, bA, bB);
      G1ITER(2 * kp + 1, As1, As0, bB, bA);
    }
  }
  // ---------- phase 1: t (+w0) -> R1[128][512] unswizzled ----------
#pragma unroll
  for (int ni = 0; ni < 4; ++ni) {
    const int col = w * 64 + ni * 16 + lr;
    const float b0 = w0[col];
#pragma unroll
    for (int mi = 0; mi < 8; ++mi)
#pragma unroll
      for (int r = 0; r < 4; ++r)
        R1[(mi * 16 + kg * 4 + r) * DD + col] = f2bf(acc[mi][ni][r] + b0);
  }
  BAR_LGKM();
  // ---------- phase 2: attention, 2-row batched; masks pre-balloted ----------
  const float scale = 0.044194173824159216f;  // 512^-0.5
  const size_t wb0 = (size_t)bm * 128 + w * 16;
  unsigned long long mlo, mhi;
  {
    const int* mbase = mask + wb0 * KM;       // 80 ints for this wave's 16 rows
    const int v0 = mbase[lane];
    const int v1 = (lane < 16) ? mbase[64 + lane] : 0;
    mlo = __ballot(v0 != 0);
    mhi = __ballot(v1 != 0) & 0xFFFFull;      // bits 0..15 = flat idx 64..79
  }
  for (int rr = 0; rr < 16; rr += 2) {
    const int row0 = w * 16 + rr;
    const size_t b0 = wb0 + rr;
    const short8 tv0 = *(const short8*)&R1[row0 * DD + lane * 8];
    const short8 tv1 = *(const short8*)&R1[(row0 + 1) * DD + lane * 8];
    float tf0[8], tf1[8];
#pragma unroll
    for (int i = 0; i < 8; ++i) { tf0[i] = bf2f(tv0[i]); tf1[i] = bf2f(tv1[i]); }
    // vm bits from pre-balloted words (uniform scalars; no loads in the loop)
    const int sh0 = rr * 5, sh1 = sh0 + 5;
    const int vm0 = (sh0 <= 55) ? (int)((mlo >> sh0) & 31)
                  : (sh0 == 60) ? (int)(((mlo >> 60) | (mhi << 4)) & 31)
                                : (int)((mhi >> (sh0 - 64)) & 31);
    const int vm1 = (sh1 <= 55) ? (int)((mlo >> sh1) & 31)
                  : (sh1 == 60) ? (int)(((mlo >> 60) | (mhi << 4)) & 31)
                                : (int)((mhi >> (sh1 - 64)) & 31);
    f32x4 ma0[KM], mc0[KM], ma1[KM], mc1[KM];
#pragma unroll
    for (int k = 0; k < KM; ++k) {
      if (vm0 & (1 << k)) {
        const f32x4* mp = (const f32x4*)(mem + (b0 * KM + k) * DD + lane * 8);
        ma0[k] = __builtin_nontemporal_load(mp);
        mc0[k] = __builtin_nontemporal_load(mp + 1);
      }
      if (vm1 & (1 << k)) {
        const f32x4* mp = (const f32x4*)(mem + ((b0 + 1) * KM + k) * DD + lane * 8);
        ma1[k] = __builtin_nontemporal_load(mp);
        mc1[k] = __builtin_nontemporal_load(mp + 1);
      }
    }
    float s0[KM], s1[KM];
#pragma unroll
    for (int k = 0; k < KM; ++k) {
      if (vm0 & (1 << k)) {
        float p = 0.f;
#pragma unroll
        for (int i = 0; i < 4; ++i) { p += tf0[i] * ma0[k][i]; p += tf0[4 + i] * mc0[k][i]; }
#pragma unroll
        for (int off = 32; off > 0; off >>= 1) p += __shfl_xor(p, off);
        s0[k] = p * scale;
      }
      if (vm1 & (1 << k)) {
        float p = 0.f;
#pragma unroll
        for (int i = 0; i < 4; ++i) { p += tf1[i] * ma1[k][i]; p += tf1[4 + i] * mc1[k][i]; }
#pragma unroll
        for (int off = 32; off > 0; off >>= 1) p += __shfl_xor(p, off);
        s1[k] = p * scale;
      }
    }
    ROW_FINISH(s0, ma0, mc0, vm0, row0)
    ROW_FINISH(s1, ma1, mc1, vm1, (row0 + 1))
  }
  BAR_LGKM();
  // ---------- phase 3: GEMM2  memO = mbar @ C  (barrier-free k-loop) ----------
  f32x4 acc2[8][4] = {};
  {
    short8 cA[4], cB[4];
#pragma unroll
    for (int ni = 0; ni < 4; ++ni) cA[ni] = *(const short8*)(ctb + ni * 512);
    for (int kp = 0; kp < 8; ++kp) {
      G2ITER(2 * kp,     cA, cB);
      G2ITER(2 * kp + 1, cB, cA);
    }
  }
  BAR_LGKM();                         // all waves' R1 reads done before overwrite
  // ---------- phase 4: memO (+d0) -> R1 unswizzled ----------
#pragma unroll
  for (int ni = 0; ni < 4; ++ni) {
    const int col = w * 64 + ni * 16 + lr;
    const float b0 = d0[col];
#pragma unroll
    for (int mi = 0; mi < 8; ++mi)
#pragma unroll
      for (int r = 0; r < 4; ++r)
        R1[(mi * 16 + kg * 4 + r) * DD + col] = f2bf(acc2[mi][ni][r] + b0);
  }
  BAR_LGKM();
  // ---------- phase 5: gate/conf/residual/LayerNorm -> out ----------
  {
    const float* wg1 = Wg + lane * 8;
    const float* wg2 = Wg + DD + lane * 8;
    f32x4 g1a = *(const f32x4*)wg1, g1b = *(const f32x4*)(wg1 + 4);
    f32x4 g2a = *(const f32x4*)wg2, g2b = *(const f32x4*)(wg2 + 4);
    f32x4 la = *(const f32x4*)(lng + lane * 8), lb4 = *(const f32x4*)(lng + lane * 8 + 4);
    f32x4 ba = *(const f32x4*)(lnb + lane * 8), bb4 = *(const f32x4*)(lnb + lane * 8 + 4);
    const float bgs = bgp[0];
    for (int rr = 0; rr < 16; ++rr) {
      const int row = w * 16 + rr;
      const size_t b = (size_t)bm * 128 + row;
      const float* qp = q + b * DD + lane * 8;
      f32x4 q0 = *(const f32x4*)qp;
      f32x4 q1 = *(const f32x4*)(qp + 4);
      float qf[8] = {q0[0],q0[1],q0[2],q0[3],q1[0],q1[1],q1[2],q1[3]};
      const short8 mv = *(const short8*)&R1[row * DD + lane * 8];
      float mf[8];
#pragma unroll
      for (int i = 0; i < 8; ++i) mf[i] = bf2f(mv[i]);
      float gp = qf[0]*g1a[0]+qf[1]*g1a[1]+qf[2]*g1a[2]+qf[3]*g1a[3]
               + qf[4]*g1b[0]+qf[5]*g1b[1]+qf[6]*g1b[2]+qf[7]*g1b[3]
               + mf[0]*g2a[0]+mf[1]*g2a[1]+mf[2]*g2a[2]+mf[3]*g2a[3]
               + mf[4]*g2b[0]+mf[5]*g2b[1]+mf[6]*g2b[2]+mf[7]*g2b[3];
#pragma unroll
      for (int off = 32; off > 0; off >>= 1) gp += __shfl_xor(gp, off);
      const float gate = 1.f / (1.f + __expf(-(gp + bgs)));
      float ms = sims[b * KM];
#pragma unroll
      for (int k = 1; k < KM; ++k) ms = fmaxf(ms, sims[b * KM + k]);
      const float conf = 1.f / (1.f + __expf(-(ms - 0.7f)));
      const float gc = gate * conf;
      float o[8];
      float s1 = 0.f, s2 = 0.f;
#pragma unroll
      for (int i = 0; i < 8; ++i) {
        o[i] = qf[i] + gc * mf[i];
        s1 += o[i];
        s2 += o[i] * o[i];
      }
#pragma unroll
      for (int off = 32; off > 0; off >>= 1) { s1 += __shfl_xor(s1, off); s2 += __shfl_xor(s2, off); }
      const float mu = s1 * (1.f / 512.f);
      const float var = s2 * (1.f / 512.f) - mu * mu;
      const float rs = rsqrtf(var + 1e-5f);
      f32x4 r0, r1;
#pragma unroll
      for (int i = 0; i < 4; ++i) r0[i] = (o[i] - mu) * rs * la[i] + ba[i];
#pragma unroll
      for (int i = 0; i < 4; ++i) r1[i] = (o[4 + i] - mu) * rs * lb4[i] + bb4[i];
      float* op = outp + b * DD + lane * 8;
      __builtin_nontemporal_store(r0, (f32x4*)op);
      __builtin_nontemporal_store(r1, (f32x4*)(op + 4));
    }
  }
}

extern "C" void kernel_launch(void* const* d_in, const int* in_sizes, int n_in,
                              void* d_out, int out_size, void* d_ws, size_t ws_size,
                              hipStream_t stream) {
  const float* query = (const float*)d_in[0];
  const float* mem   = (const float*)d_in[1];
  const float* sims  = (const float*)d_in[2];
  const int*   mask  = (const int*)d_in[3];
  const float* Wq = (const float*)d_in[4];
  const float* bq = (const float*)d_in[5];
  const float* Wk = (const float*)d_in[6];
  // d_in[7] = bk: irrelevant (per-row constant on scores; softmax shift-invariant)
  const float* Wv = (const float*)d_in[8];
  const float* bv = (const float*)d_in[9];
  const float* Wo = (const float*)d_in[10];
  const float* bo = (const float*)d_in[11];
  const float* Wg = (const float*)d_in[12];
  const float* bg = (const float*)d_in[13];
  const float* ln_g = (const float*)d_in[14];
  const float* ln_b = (const float*)d_in[15];
  float* out = (float*)d_out;

  char* ws = (char*)d_ws;
  short* AtP = (short*)ws;                              // 512 KB packed [16][512][32] bf16
  short* CtP = AtP + (size_t)DD * DD;                   // 512 KB packed
  float* w0 = (float*)(CtP + (size_t)DD * DD);          // 2 KB
  float* d0 = w0 + DD;                                  // 2 KB

  prepG<<<dim3(130), dim3(512), 0, stream>>>(Wq, bq, Wk, Wv, Wo, bo, bv, AtP, CtP, w0, d0);
  mk<<<dim3(B_ROWS / 128), dim3(512), 0, stream>>>(query, AtP, w0, mem, mask,
                                                   CtP, d0, sims, Wg, bg, ln_g, ln_b, out);
}

// Round 17
// 135.727 us; speedup vs baseline: 1.0176x; 1.0176x over previous
//
#include <hip/hip_runtime.h>

#define DD 512
#define KM 5
#define B_ROWS 32768

typedef __attribute__((ext_vector_type(8))) short short8;
typedef __attribute__((ext_vector_type(4))) short s16x4;
typedef __attribute__((ext_vector_type(4))) float f32x4;

static __device__ __forceinline__ short f2bf(float x) {
  unsigned u = __builtin_bit_cast(unsigned, x);
  u = (u + 0x7fffu + ((u >> 16) & 1u)) >> 16;
  return (short)u;
}
static __device__ __forceinline__ float bf2f(short s) {
  unsigned u = ((unsigned)(unsigned short)s) << 16;
  return __builtin_bit_cast(float, u);
}

// lgkm-only barrier: LDS ordered; global loads stay in flight
#define BAR_LGKM() do { asm volatile("s_waitcnt lgkmcnt(0)" ::: "memory"); __builtin_amdgcn_s_barrier(); } while (0)

// ---------------- prepG: At/Ct via MFMA (64 blocks, PACKED output) + w0 + d0 ----------------
// Packed layout: P[ki][j][kk] (ki = col>>5, kk = col&31) — wave B-frag = contiguous 1 KB.
__global__ __launch_bounds__(512, 2)
void prepG(const float* __restrict__ Wq, const float* __restrict__ bq,
           const float* __restrict__ Wk, const float* __restrict__ Wv,
           const float* __restrict__ Wo, const float* __restrict__ bo,
           const float* __restrict__ bv,
           short* __restrict__ At, short* __restrict__ Ct,
           float* __restrict__ w0, float* __restrict__ d0) {
  __shared__ short sh[12288];          // 24 KB: As dbuf 2x8KB + Bs dbuf 2x4KB
  const int tid = threadIdx.x;
  const int blk = blockIdx.x;
  if (blk < 64) {
    const bool isC = blk >= 32;
    const int b = blk & 31;
    const int j0 = (b >> 3) * 128;     // M tile (output rows j)
    const int i0 = (b & 7) * 64;       // N tile (output cols i)
    const int lane = tid & 63;
    const int w = tid >> 6;
    const int wm = w & 1, wn = w >> 1; // wave grid 2M x 4N
    const int kg = lane >> 4, lr = lane & 15;
    const float* Ysrc = isC ? Wv : Wq;
    f32x4 acc[4] = {};
    f32x4 ra0, ra1;
    f32x4 rbv;
    if (!isC) {
      const float* p = Wk + (size_t)(j0 + (tid >> 2)) * DD + (tid & 3) * 8;
      ra0 = *(const f32x4*)p; ra1 = *(const f32x4*)(p + 4);
    } else {
      const float* p = Wo + (size_t)(tid >> 4) * DD + j0 + (tid & 15) * 8;
      ra0 = *(const f32x4*)p; ra1 = *(const f32x4*)(p + 4);
    }
    rbv = *(const f32x4*)(Ysrc + (size_t)(i0 + (tid >> 3)) * DD + (tid & 7) * 4);
    for (int ki = 0; ki < 16; ++ki) {
      short* As = (ki & 1) ? (sh + 4096) : sh;             // [128][32]
      short* Bs = (ki & 1) ? (sh + 10240) : (sh + 8192);   // [64][32]
      if (!isC) {
        short8 sv;
        sv[0]=f2bf(ra0[0]); sv[1]=f2bf(ra0[1]); sv[2]=f2bf(ra0[2]); sv[3]=f2bf(ra0[3]);
        sv[4]=f2bf(ra1[0]); sv[5]=f2bf(ra1[1]); sv[6]=f2bf(ra1[2]); sv[7]=f2bf(ra1[3]);
        *(short8*)&As[(tid >> 2) * 32 + (((tid & 3) * 8) ^ (((tid >> 2) & 3) << 3))] = sv;
      } else {
        const int e = tid >> 4;
#pragma unroll
        for (int c = 0; c < 8; ++c) {
          const int j = (tid & 15) * 8 + c;
          const float v = (c < 4) ? ra0[c & 3] : ra1[c & 3];
          As[j * 32 + (e ^ ((j & 3) << 3))] = f2bf(v);
        }
      }
      {
        s16x4 sv;
        sv[0]=f2bf(rbv[0]); sv[1]=f2bf(rbv[1]); sv[2]=f2bf(rbv[2]); sv[3]=f2bf(rbv[3]);
        *(s16x4*)&Bs[(tid >> 3) * 32 + (((tid & 7) * 4) ^ (((tid >> 3) & 3) << 3))] = sv;
      }
      if (ki < 15) {
        const int kt = (ki + 1) * 32;
        if (!isC) {
          const float* p = Wk + (size_t)(j0 + (tid >> 2)) * DD + kt + (tid & 3) * 8;
          ra0 = *(const f32x4*)p; ra1 = *(const f32x4*)(p + 4);
        } else {
          const float* p = Wo + (size_t)(kt + (tid >> 4)) * DD + j0 + (tid & 15) * 8;
          ra0 = *(const f32x4*)p; ra1 = *(const f32x4*)(p + 4);
        }
        rbv = *(const f32x4*)(Ysrc + (size_t)(i0 + (tid >> 3)) * DD + kt + (tid & 7) * 4);
      }
      __syncthreads();
      short8 av[4], bvv;
#pragma unroll
      for (int mi = 0; mi < 4; ++mi) {
        const int ar = wm * 64 + mi * 16 + lr;
        av[mi] = *(const short8*)&As[ar * 32 + ((kg * 8) ^ ((lr & 3) << 3))];
      }
      {
        const int br = wn * 16 + lr;
        bvv = *(const short8*)&Bs[br * 32 + ((kg * 8) ^ ((lr & 3) << 3))];
      }
#pragma unroll
      for (int mi = 0; mi < 4; ++mi)
        acc[mi] = __builtin_amdgcn_mfma_f32_16x16x32_bf16(av[mi], bvv, acc[mi], 0, 0, 0);
      __syncthreads();
    }
    short* P = isC ? Ct : At;
    const int cwl = wn * 16 + lr;
    const int kiv = (b & 7) * 2 + (cwl >> 5);
    const int kkv = cwl & 31;
#pragma unroll
    for (int mi = 0; mi < 4; ++mi)
#pragma unroll
      for (int r = 0; r < 4; ++r) {
        const int j = j0 + wm * 64 + mi * 16 + kg * 4 + r;
        P[(size_t)kiv * 16384 + j * 32 + kkv] = f2bf(acc[mi][r]);
      }
  } else if (blk < 128) {
    const int j = (blk - 64) * 8 + (tid >> 6);
    const int lane = tid & 63;
    const float* r = Wk + (size_t)j * DD + lane * 8;
    f32x4 a = *(const f32x4*)r;
    f32x4 c = *(const f32x4*)(r + 4);
    const float* bp = bq + lane * 8;
    f32x4 ba = *(const f32x4*)bp;
    f32x4 bc = *(const f32x4*)(bp + 4);
    float s = a[0]*ba[0] + a[1]*ba[1] + a[2]*ba[2] + a[3]*ba[3]
            + c[0]*bc[0] + c[1]*bc[1] + c[2]*bc[2] + c[3]*bc[3];
#pragma unroll
    for (int off = 32; off > 0; off >>= 1) s += __shfl_xor(s, off);
    if (lane == 0) w0[j] = s;
  } else {
    float* red = (float*)sh;     // [2][256]
    const int j = (blk - 128) * 256 + (tid & 255);
    const int half = tid >> 8;
    float s = 0.f;
    for (int e = half * 256; e < half * 256 + 256; ++e)
      s += bv[e] * Wo[(size_t)e * DD + j];
    red[half * 256 + (tid & 255)] = s;
    __syncthreads();
    if (half == 0) d0[j] = red[tid] + red[256 + tid] + bo[j];
  }
}

// write one 64x32 A k-slice chunk (4 bf16) from one f32x4
#define WRITE_A4(DST, QV) do {                                              \
  s16x4 _sv;                                                                \
  _sv[0]=f2bf((QV)[0]); _sv[1]=f2bf((QV)[1]);                               \
  _sv[2]=f2bf((QV)[2]); _sv[3]=f2bf((QV)[3]);                               \
  *(s16x4*)&(DST)[arow * 32 + (acol ^ ((arow & 3) << 3))] = _sv; } while (0)

// GEMM1 iter (BM=64): B-frag prefetch ping-pong; A-frags read per-mi (low VGPR)
#define G1ITER(KI, ASC, ASN, BC, BN) do {                                   \
    if ((KI) < 15) {                                                        \
      _Pragma("unroll") for (int ni = 0; ni < 4; ++ni)                      \
        (BN)[ni] = *(const short8*)(atb + ((KI) + 1) * 16384 + ni * 512);   \
      WRITE_A4(ASN, qA);                                                    \
    }                                                                       \
    if ((KI) < 14) qA = *(const f32x4*)(qbase + ((KI) + 2) * 32);           \
    _Pragma("unroll") for (int mi = 0; mi < 4; ++mi) {                      \
      const int ar = mi * 16 + lr;                                          \
      const short8 av = *(const short8*)&(ASC)[ar * 32 + ((kg * 8) ^ ((lr & 3) << 3))]; \
      _Pragma("unroll") for (int ni = 0; ni < 4; ++ni)                      \
        acc[mi][ni] = __builtin_amdgcn_mfma_f32_16x16x32_bf16(av, (BC)[ni], acc[mi][ni], 0, 0, 0); \
    }                                                                       \
    BAR_LGKM();                                                             \
  } while (0)

// GEMM2 iter: A from R1 (swizzled, read-only), B prefetch ping-pong — NO barriers
#define G2ITER(KI, BC, BN) do {                                             \
    if ((KI) < 15) {                                                        \
      _Pragma("unroll") for (int ni = 0; ni < 4; ++ni)                      \
        (BN)[ni] = *(const short8*)(ctb + ((KI) + 1) * 16384 + ni * 512);   \
    }                                                                       \
    _Pragma("unroll") for (int mi = 0; mi < 4; ++mi) {                      \
      const int ar = mi * 16 + lr;                                          \
      const short8 av = *(const short8*)&R1[(ar * DD + (KI) * 32 + kg * 8) ^ ((ar & 7) << 3)]; \
      _Pragma("unroll") for (int ni = 0; ni < 4; ++ni)                      \
        acc2[mi][ni] = __builtin_amdgcn_mfma_f32_16x16x32_bf16(av, (BC)[ni], acc2[mi][ni], 0, 0, 0); \
    }                                                                       \
  } while (0)

// softmax+weighted-sum finisher; writes mbar row into R1 with (row&7)<<3 swizzle
#define ROW_FINISH(SV, MA, MC, VM, ROW)                                     \
    {                                                                       \
      float mx = -1e30f;                                                    \
      _Pragma("unroll") for (int k = 0; k < KM; ++k)                        \
        if ((VM) & (1 << k)) mx = fmaxf(mx, SV[k]);                         \
      float wk[KM]; float sum = 0.f;                                        \
      _Pragma("unroll") for (int k = 0; k < KM; ++k) {                      \
        wk[k] = ((VM) & (1 << k)) ? __expf(SV[k] - mx) : 0.f;               \
        sum += wk[k];                                                       \
      }                                                                     \
      const float inv = 1.f / sum;                                          \
      float o[8] = {0.f,0.f,0.f,0.f,0.f,0.f,0.f,0.f};                       \
      _Pragma("unroll") for (int k = 0; k < KM; ++k)                        \
        if ((VM) & (1 << k)) {                                              \
          const float g = wk[k] * inv;                                      \
          _Pragma("unroll") for (int i = 0; i < 4; ++i) {                   \
            o[i] += g * MA[k][i]; o[4 + i] += g * MC[k][i];                 \
          }                                                                 \
        }                                                                   \
      short8 ov;                                                            \
      _Pragma("unroll") for (int i = 0; i < 8; ++i) ov[i] = f2bf(o[i]);     \
      *(short8*)&R1[((ROW) * DD + lane * 8) ^ (((ROW) & 7) << 3)] = ov;     \
    }

// Fused megakernel, 64 rows/block, 8 waves, grid 512 (2 blocks/CU: phase overlap).
// LDS = R1 64 KB (As ping-pong 2x4KB aliased at head during GEMM1; t -> mbar(swz) -> memO).
__global__ __launch_bounds__(512, 4)
void mk(const float* __restrict__ q, const short* __restrict__ AtP,
        const float* __restrict__ w0, const float* __restrict__ mem,
        const int* __restrict__ mask, const short* __restrict__ CtP,
        const float* __restrict__ d0, const float* __restrict__ sims,
        const float* __restrict__ Wg, const float* __restrict__ bgp,
        const float* __restrict__ lng, const float* __restrict__ lnb,
        float* __restrict__ outp) {
  __shared__ short R1[64 * DD];      // 64 KB
  const int tid = threadIdx.x;
  const int lane = tid & 63;
  const int w = tid >> 6;
  const int kg = lane >> 4, lr = lane & 15;
  const int bm = blockIdx.x;

  short* As0 = R1;                   // [64][32] 4 KB
  short* As1 = R1 + 2048;            // 4 KB

  const short* atb = AtP + (size_t)(w * 64 + lr) * 32 + kg * 8;
  const short* ctb = CtP + (size_t)(w * 64 + lr) * 32 + kg * 8;

  // ---------- phase 0: GEMM1  t = q @ A  (B prefetch ping-pong) ----------
  f32x4 acc[4][4] = {};
  const int arow = tid >> 3, acol = (tid & 7) * 4;
  const float* qbase = q + (size_t)(bm * 64 + arow) * DD + acol;
  {
    f32x4 qA = *(const f32x4*)qbase;
    WRITE_A4(As0, qA);
    qA = *(const f32x4*)(qbase + 32);
    short8 bA[4], bB[4];
#pragma unroll
    for (int ni = 0; ni < 4; ++ni) bA[ni] = *(const short8*)(atb + ni * 512);
    BAR_LGKM();
    for (int kp = 0; kp < 8; ++kp) {
      G1ITER(2 * kp,     As0, As1, bA, bB);
      G1ITER(2 * kp + 1, As1, As0, bB, bA);
    }
  }
  // ---------- phase 1: t (+w0) -> R1[64][512] unswizzled ----------
#pragma unroll
  for (int ni = 0; ni < 4; ++ni) {
    const int col = w * 64 + ni * 16 + lr;
    const float b0 = w0[col];
#pragma unroll
    for (int mi = 0; mi < 4; ++mi)
#pragma unroll
      for (int r = 0; r < 4; ++r)
        R1[(mi * 16 + kg * 4 + r) * DD + col] = f2bf(acc[mi][ni][r] + b0);
  }
  BAR_LGKM();
  // ---------- phase 2: attention, 1 row/iter; t -> mbar in place (swizzled) ----------
  const float scale = 0.044194173824159216f;  // 512^-0.5
  for (int rr = 0; rr < 8; ++rr) {
    const int row = w * 8 + rr;
    const size_t b = (size_t)bm * 64 + row;
    const short8 tv = *(const short8*)&R1[row * DD + lane * 8];
    float tf[8];
#pragma unroll
    for (int i = 0; i < 8; ++i) tf[i] = bf2f(tv[i]);
    int vm = 0;
#pragma unroll
    for (int k = 0; k < KM; ++k)
      vm |= (__builtin_amdgcn_readfirstlane(mask[b * KM + k]) ? 1 : 0) << k;
    f32x4 ma[KM], mc[KM];
#pragma unroll
    for (int k = 0; k < KM; ++k)
      if (vm & (1 << k)) {
        const f32x4* mp = (const f32x4*)(mem + (b * KM + k) * DD + lane * 8);
        ma[k] = __builtin_nontemporal_load(mp);
        mc[k] = __builtin_nontemporal_load(mp + 1);
      }
    float s[KM];
#pragma unroll
    for (int k = 0; k < KM; ++k)
      if (vm & (1 << k)) {
        float p = 0.f;
#pragma unroll
        for (int i = 0; i < 4; ++i) { p += tf[i] * ma[k][i]; p += tf[4 + i] * mc[k][i]; }
#pragma unroll
        for (int off = 32; off > 0; off >>= 1) p += __shfl_xor(p, off);
        s[k] = p * scale;
      }
    ROW_FINISH(s, ma, mc, vm, row)
  }
  BAR_LGKM();
  // ---------- phase 3: GEMM2  memO = mbar @ C  (barrier-free k-loop) ----------
  f32x4 acc2[4][4] = {};
  {
    short8 cA[4], cB[4];
#pragma unroll
    for (int ni = 0; ni < 4; ++ni) cA[ni] = *(const short8*)(ctb + ni * 512);
    for (int kp = 0; kp < 8; ++kp) {
      G2ITER(2 * kp,     cA, cB);
      G2ITER(2 * kp + 1, cB, cA);
    }
  }
  BAR_LGKM();                         // all waves' R1 reads done before overwrite
  // ---------- phase 4: memO (+d0) -> R1 unswizzled ----------
#pragma unroll
  for (int ni = 0; ni < 4; ++ni) {
    const int col = w * 64 + ni * 16 + lr;
    const float b0 = d0[col];
#pragma unroll
    for (int mi = 0; mi < 4; ++mi)
#pragma unroll
      for (int r = 0; r < 4; ++r)
        R1[(mi * 16 + kg * 4 + r) * DD + col] = f2bf(acc2[mi][ni][r] + b0);
  }
  BAR_LGKM();
  // ---------- phase 5: gate/conf/residual/LayerNorm -> out ----------
  {
    const float* wg1 = Wg + lane * 8;
    const float* wg2 = Wg + DD + lane * 8;
    f32x4 g1a = *(const f32x4*)wg1, g1b = *(const f32x4*)(wg1 + 4);
    f32x4 g2a = *(const f32x4*)wg2, g2b = *(const f32x4*)(wg2 + 4);
    f32x4 la = *(const f32x4*)(lng + lane * 8), lb4 = *(const f32x4*)(lng + lane * 8 + 4);
    f32x4 ba = *(const f32x4*)(lnb + lane * 8), bb4 = *(const f32x4*)(lnb + lane * 8 + 4);
    const float bgs = bgp[0];
    for (int rr = 0; rr < 8; ++rr) {
      const int row = w * 8 + rr;
      const size_t b = (size_t)bm * 64 + row;
      const float* qp = q + b * DD + lane * 8;
      f32x4 q0 = *(const f32x4*)qp;
      f32x4 q1 = *(const f32x4*)(qp + 4);
      float qf[8] = {q0[0],q0[1],q0[2],q0[3],q1[0],q1[1],q1[2],q1[3]};
      const short8 mv = *(const short8*)&R1[row * DD + lane * 8];
      float mf[8];
#pragma unroll
      for (int i = 0; i < 8; ++i) mf[i] = bf2f(mv[i]);
      float gp = qf[0]*g1a[0]+qf[1]*g1a[1]+qf[2]*g1a[2]+qf[3]*g1a[3]
               + qf[4]*g1b[0]+qf[5]*g1b[1]+qf[6]*g1b[2]+qf[7]*g1b[3]
               + mf[0]*g2a[0]+mf[1]*g2a[1]+mf[2]*g2a[2]+mf[3]*g2a[3]
               + mf[4]*g2b[0]+mf[5]*g2b[1]+mf[6]*g2b[2]+mf[7]*g2b[3];
#pragma unroll
      for (int off = 32; off > 0; off >>= 1) gp += __shfl_xor(gp, off);
      const float gate = 1.f / (1.f + __expf(-(gp + bgs)));
      float ms = sims[b * KM];
#pragma unroll
      for (int k = 1; k < KM; ++k) ms = fmaxf(ms, sims[b * KM + k]);
      const float conf = 1.f / (1.f + __expf(-(ms - 0.7f)));
      const float gc = gate * conf;
      float o[8];
      float s1 = 0.f, s2 = 0.f;
#pragma unroll
      for (int i = 0; i < 8; ++i) {
        o[i] = qf[i] + gc * mf[i];
        s1 += o[i];
        s2 += o[i] * o[i];
      }
#pragma unroll
      for (int off = 32; off > 0; off >>= 1) { s1 += __shfl_xor(s1, off); s2 += __shfl_xor(s2, off); }
      const float mu = s1 * (1.f / 512.f);
      const float var = s2 * (1.f / 512.f) - mu * mu;
      const float rs = rsqrtf(var + 1e-5f);
      f32x4 r0, r1;
#pragma unroll
      for (int i = 0; i < 4; ++i) r0[i] = (o[i] - mu) * rs * la[i] + ba[i];
#pragma unroll
      for (int i = 0; i < 4; ++i) r1[i] = (o[4 + i] - mu) * rs * lb4[i] + bb4[i];
      float* op = outp + b * DD + lane * 8;
      __builtin_nontemporal_store(r0, (f32x4*)op);
      __builtin_nontemporal_store(r1, (f32x4*)(op + 4));
    }
  }
}

extern "C" void kernel_launch(void* const* d_in, const int* in_sizes, int n_in,
                              void* d_out, int out_size, void* d_ws, size_t ws_size,
                              hipStream_t stream) {
  const float* query = (const float*)d_in[0];
  const float* mem   = (const float*)d_in[1];
  const float* sims  = (const float*)d_in[2];
  const int*   mask  = (const int*)d_in[3];
  const float* Wq = (const float*)d_in[4];
  const float* bq = (const float*)d_in[5];
  const float* Wk = (const float*)d_in[6];
  // d_in[7] = bk: irrelevant (per-row constant on scores; softmax shift-invariant)
  const float* Wv = (const float*)d_in[8];
  const float* bv = (const float*)d_in[9];
  const float* Wo = (const float*)d_in[10];
  const float* bo = (const float*)d_in[11];
  const float* Wg = (const float*)d_in[12];
  const float* bg = (const float*)d_in[13];
  const float* ln_g = (const float*)d_in[14];
  const float* ln_b = (const float*)d_in[15];
  float* out = (float*)d_out;

  char* ws = (char*)d_ws;
  short* AtP = (short*)ws;                              // 512 KB packed [16][512][32] bf16
  short* CtP = AtP + (size_t)DD * DD;                   // 512 KB packed
  float* w0 = (float*)(CtP + (size_t)DD * DD);          // 2 KB
  float* d0 = w0 + DD;                                  // 2 KB

  prepG<<<dim3(130), dim3(512), 0, stream>>>(Wq, bq, Wk, Wv, Wo, bo, bv, AtP, CtP, w0, d0);
  mk<<<dim3(B_ROWS / 64), dim3(512), 0, stream>>>(query, AtP, w0, mem, mask,
                                                  CtP, d0, sims, Wg, bg, ln_g, ln_b, out);
}

// Round 18
// 130.381 us; speedup vs baseline: 1.0594x; 1.0410x over previous
//
#include <hip/hip_runtime.h>

#define DD 512
#define KM 5
#define B_ROWS 32768

typedef __attribute__((ext_vector_type(8))) short short8;
typedef __attribute__((ext_vector_type(4))) short s16x4;
typedef __attribute__((ext_vector_type(4))) float f32x4;

static __device__ __forceinline__ short f2bf(float x) {
  unsigned u = __builtin_bit_cast(unsigned, x);
  u = (u + 0x7fffu + ((u >> 16) & 1u)) >> 16;
  return (short)u;
}
static __device__ __forceinline__ float bf2f(short s) {
  unsigned u = ((unsigned)(unsigned short)s) << 16;
  return __builtin_bit_cast(float, u);
}

// lgkm-only barrier: LDS ordered; global loads stay in flight
#define BAR_LGKM() do { asm volatile("s_waitcnt lgkmcnt(0)" ::: "memory"); __builtin_amdgcn_s_barrier(); } while (0)

// ---------------- prepG: At/Ct via MFMA (64 blocks, PACKED output) + w0 + d0 ----------------
// Packed layout: P[ki][j][kk] (ki = col>>5, kk = col&31) — wave B-frag = contiguous 1 KB.
__global__ __launch_bounds__(512, 2)
void prepG(const float* __restrict__ Wq, const float* __restrict__ bq,
           const float* __restrict__ Wk, const float* __restrict__ Wv,
           const float* __restrict__ Wo, const float* __restrict__ bo,
           const float* __restrict__ bv,
           short* __restrict__ At, short* __restrict__ Ct,
           float* __restrict__ w0, float* __restrict__ d0) {
  __shared__ short sh[12288];          // 24 KB: As dbuf 2x8KB + Bs dbuf 2x4KB
  const int tid = threadIdx.x;
  const int blk = blockIdx.x;
  if (blk < 64) {
    const bool isC = blk >= 32;
    const int b = blk & 31;
    const int j0 = (b >> 3) * 128;     // M tile (output rows j)
    const int i0 = (b & 7) * 64;       // N tile (output cols i)
    const int lane = tid & 63;
    const int w = tid >> 6;
    const int wm = w & 1, wn = w >> 1; // wave grid 2M x 4N
    const int kg = lane >> 4, lr = lane & 15;
    const float* Ysrc = isC ? Wv : Wq;
    f32x4 acc[4] = {};
    f32x4 ra0, ra1;
    f32x4 rbv;
    if (!isC) {
      const float* p = Wk + (size_t)(j0 + (tid >> 2)) * DD + (tid & 3) * 8;
      ra0 = *(const f32x4*)p; ra1 = *(const f32x4*)(p + 4);
    } else {
      const float* p = Wo + (size_t)(tid >> 4) * DD + j0 + (tid & 15) * 8;
      ra0 = *(const f32x4*)p; ra1 = *(const f32x4*)(p + 4);
    }
    rbv = *(const f32x4*)(Ysrc + (size_t)(i0 + (tid >> 3)) * DD + (tid & 7) * 4);
    for (int ki = 0; ki < 16; ++ki) {
      short* As = (ki & 1) ? (sh + 4096) : sh;             // [128][32]
      short* Bs = (ki & 1) ? (sh + 10240) : (sh + 8192);   // [64][32]
      if (!isC) {
        short8 sv;
        sv[0]=f2bf(ra0[0]); sv[1]=f2bf(ra0[1]); sv[2]=f2bf(ra0[2]); sv[3]=f2bf(ra0[3]);
        sv[4]=f2bf(ra1[0]); sv[5]=f2bf(ra1[1]); sv[6]=f2bf(ra1[2]); sv[7]=f2bf(ra1[3]);
        *(short8*)&As[(tid >> 2) * 32 + (((tid & 3) * 8) ^ (((tid >> 2) & 3) << 3))] = sv;
      } else {
        const int e = tid >> 4;
#pragma unroll
        for (int c = 0; c < 8; ++c) {
          const int j = (tid & 15) * 8 + c;
          const float v = (c < 4) ? ra0[c & 3] : ra1[c & 3];
          As[j * 32 + (e ^ ((j & 3) << 3))] = f2bf(v);
        }
      }
      {
        s16x4 sv;
        sv[0]=f2bf(rbv[0]); sv[1]=f2bf(rbv[1]); sv[2]=f2bf(rbv[2]); sv[3]=f2bf(rbv[3]);
        *(s16x4*)&Bs[(tid >> 3) * 32 + (((tid & 7) * 4) ^ (((tid >> 3) & 3) << 3))] = sv;
      }
      if (ki < 15) {
        const int kt = (ki + 1) * 32;
        if (!isC) {
          const float* p = Wk + (size_t)(j0 + (tid >> 2)) * DD + kt + (tid & 3) * 8;
          ra0 = *(const f32x4*)p; ra1 = *(const f32x4*)(p + 4);
        } else {
          const float* p = Wo + (size_t)(kt + (tid >> 4)) * DD + j0 + (tid & 15) * 8;
          ra0 = *(const f32x4*)p; ra1 = *(const f32x4*)(p + 4);
        }
        rbv = *(const f32x4*)(Ysrc + (size_t)(i0 + (tid >> 3)) * DD + kt + (tid & 7) * 4);
      }
      __syncthreads();
      short8 av[4], bvv;
#pragma unroll
      for (int mi = 0; mi < 4; ++mi) {
        const int ar = wm * 64 + mi * 16 + lr;
        av[mi] = *(const short8*)&As[ar * 32 + ((kg * 8) ^ ((lr & 3) << 3))];
      }
      {
        const int br = wn * 16 + lr;
        bvv = *(const short8*)&Bs[br * 32 + ((kg * 8) ^ ((lr & 3) << 3))];
      }
#pragma unroll
      for (int mi = 0; mi < 4; ++mi)
        acc[mi] = __builtin_amdgcn_mfma_f32_16x16x32_bf16(av[mi], bvv, acc[mi], 0, 0, 0);
      __syncthreads();
    }
    short* P = isC ? Ct : At;
    const int cwl = wn * 16 + lr;
    const int kiv = (b & 7) * 2 + (cwl >> 5);
    const int kkv = cwl & 31;
#pragma unroll
    for (int mi = 0; mi < 4; ++mi)
#pragma unroll
      for (int r = 0; r < 4; ++r) {
        const int j = j0 + wm * 64 + mi * 16 + kg * 4 + r;
        P[(size_t)kiv * 16384 + j * 32 + kkv] = f2bf(acc[mi][r]);
      }
  } else if (blk < 128) {
    const int j = (blk - 64) * 8 + (tid >> 6);
    const int lane = tid & 63;
    const float* r = Wk + (size_t)j * DD + lane * 8;
    f32x4 a = *(const f32x4*)r;
    f32x4 c = *(const f32x4*)(r + 4);
    const float* bp = bq + lane * 8;
    f32x4 ba = *(const f32x4*)bp;
    f32x4 bc = *(const f32x4*)(bp + 4);
    float s = a[0]*ba[0] + a[1]*ba[1] + a[2]*ba[2] + a[3]*ba[3]
            + c[0]*bc[0] + c[1]*bc[1] + c[2]*bc[2] + c[3]*bc[3];
#pragma unroll
    for (int off = 32; off > 0; off >>= 1) s += __shfl_xor(s, off);
    if (lane == 0) w0[j] = s;
  } else {
    float* red = (float*)sh;     // [2][256]
    const int j = (blk - 128) * 256 + (tid & 255);
    const int half = tid >> 8;
    float s = 0.f;
    for (int e = half * 256; e < half * 256 + 256; ++e)
      s += bv[e] * Wo[(size_t)e * DD + j];
    red[half * 256 + (tid & 255)] = s;
    __syncthreads();
    if (half == 0) d0[j] = red[tid] + red[256 + tid] + bo[j];
  }
}

// write one 128x32 A k-slice row-chunk (8 bf16) from two f32x4
#define WRITE_A(DST, QLO, QHI) do {                                                \
  short8 _sv;                                                                      \
  _sv[0]=f2bf((QLO)[0]); _sv[1]=f2bf((QLO)[1]); _sv[2]=f2bf((QLO)[2]); _sv[3]=f2bf((QLO)[3]); \
  _sv[4]=f2bf((QHI)[0]); _sv[5]=f2bf((QHI)[1]); _sv[6]=f2bf((QHI)[2]); _sv[7]=f2bf((QHI)[3]); \
  *(short8*)&(DST)[arow * 32 + (acol ^ ((arow & 3) << 3))] = _sv; } while (0)

// GEMM1 iter: A frags (LDS ping-pong), B frags prefetched from packed global, q reg ping
#define G1ITER(KI, ASC, ASN, BC, BN) do {                                   \
    short8 av[8];                                                           \
    _Pragma("unroll") for (int mi = 0; mi < 8; ++mi) {                      \
      const int ar = mi * 16 + lr;                                          \
      av[mi] = *(const short8*)&(ASC)[ar * 32 + ((kg * 8) ^ ((lr & 3) << 3))]; \
    }                                                                       \
    if ((KI) < 15) { WRITE_A(ASN, qA, qB); }                                \
    if ((KI) < 15) {                                                        \
      _Pragma("unroll") for (int ni = 0; ni < 4; ++ni)                      \
        (BN)[ni] = *(const short8*)(atb + ((KI) + 1) * 16384 + ni * 512);   \
    }                                                                       \
    if ((KI) < 14) {                                                        \
      qA = *(const f32x4*)(qbase + ((KI) + 2) * 32);                        \
      qB = *(const f32x4*)(qbase + ((KI) + 2) * 32 + 4);                    \
    }                                                                       \
    _Pragma("unroll") for (int mi = 0; mi < 8; ++mi)                        \
      _Pragma("unroll") for (int ni = 0; ni < 4; ++ni)                      \
        acc[mi][ni] = __builtin_amdgcn_mfma_f32_16x16x32_bf16(av[mi], (BC)[ni], acc[mi][ni], 0, 0, 0); \
    BAR_LGKM();                                                             \
  } while (0)

// GEMM2 iter: A from R1 (swizzled, read-only), B prefetch from global — NO barriers
#define G2ITER(KI, BC, BN) do {                                             \
    short8 av[8];                                                           \
    _Pragma("unroll") for (int mi = 0; mi < 8; ++mi) {                      \
      const int ar = mi * 16 + lr;                                          \
      av[mi] = *(const short8*)&R1[(ar * DD + (KI) * 32 + kg * 8) ^ ((ar & 7) << 3)]; \
    }                                                                       \
    if ((KI) < 15) {                                                        \
      _Pragma("unroll") for (int ni = 0; ni < 4; ++ni)                      \
        (BN)[ni] = *(const short8*)(ctb + ((KI) + 1) * 16384 + ni * 512);   \
    }                                                                       \
    _Pragma("unroll") for (int mi = 0; mi < 8; ++mi)                        \
      _Pragma("unroll") for (int ni = 0; ni < 4; ++ni)                      \
        acc2[mi][ni] = __builtin_amdgcn_mfma_f32_16x16x32_bf16(av[mi], (BC)[ni], acc2[mi][ni], 0, 0, 0); \
  } while (0)

// softmax+weighted-sum finisher; writes mbar row into R1 with (row&7)<<3 swizzle
#define ROW_FINISH(SV, MA, MC, VM, ROW)                                     \
    {                                                                       \
      float mx = -1e30f;                                                    \
      _Pragma("unroll") for (int k = 0; k < KM; ++k)                        \
        if ((VM) & (1 << k)) mx = fmaxf(mx, SV[k]);                         \
      float wk[KM]; float sum = 0.f;                                        \
      _Pragma("unroll") for (int k = 0; k < KM; ++k) {                      \
        wk[k] = ((VM) & (1 << k)) ? __expf(SV[k] - mx) : 0.f;               \
        sum += wk[k];                                                       \
      }                                                                     \
      const float inv = 1.f / sum;                                          \
      float o[8] = {0.f,0.f,0.f,0.f,0.f,0.f,0.f,0.f};                       \
      _Pragma("unroll") for (int k = 0; k < KM; ++k)                        \
        if ((VM) & (1 << k)) {                                              \
          const float g = wk[k] * inv;                                      \
          _Pragma("unroll") for (int i = 0; i < 4; ++i) {                   \
            o[i] += g * MA[k][i]; o[4 + i] += g * MC[k][i];                 \
          }                                                                 \
        }                                                                   \
      short8 ov;                                                            \
      _Pragma("unroll") for (int i = 0; i < 8; ++i) ov[i] = f2bf(o[i]);     \
      *(short8*)&R1[((ROW) * DD + lane * 8) ^ (((ROW) & 7) << 3)] = ov;     \
    }

// Fused megakernel, 128 rows/block, 8 waves, grid 256.
// LDS = R1 128 KB (As ping-pong 2x8KB aliased at head during GEMM1; t -> mbar(swz) -> memO).
__global__ __launch_bounds__(512, 2)
void mk(const float* __restrict__ q, const short* __restrict__ AtP,
        const float* __restrict__ w0, const float* __restrict__ mem,
        const int* __restrict__ mask, const short* __restrict__ CtP,
        const float* __restrict__ d0, const float* __restrict__ sims,
        const float* __restrict__ Wg, const float* __restrict__ bgp,
        const float* __restrict__ lng, const float* __restrict__ lnb,
        float* __restrict__ outp) {
  __shared__ short R1[128 * DD];     // 128 KB
  const int tid = threadIdx.x;
  const int lane = tid & 63;
  const int w = tid >> 6;
  const int kg = lane >> 4, lr = lane & 15;
  const int bm = blockIdx.x;

  short* As0 = R1;                   // [128][32] 8 KB
  short* As1 = R1 + 4096;            // 8 KB

  const short* atb = AtP + (size_t)(w * 64 + lr) * 32 + kg * 8;
  const short* ctb = CtP + (size_t)(w * 64 + lr) * 32 + kg * 8;

  // ---------- phase 0: GEMM1  t = q @ A ----------
  f32x4 acc[8][4] = {};
  const int arow = tid >> 2, acol = (tid & 3) * 8;
  const float* qbase = q + (size_t)(bm * 128 + arow) * DD + acol;
  {
    f32x4 qA = *(const f32x4*)qbase;
    f32x4 qB = *(const f32x4*)(qbase + 4);
    WRITE_A(As0, qA, qB);
    qA = *(const f32x4*)(qbase + 32);
    qB = *(const f32x4*)(qbase + 36);
    short8 bA[4], bB[4];
#pragma unroll
    for (int ni = 0; ni < 4; ++ni) bA[ni] = *(const short8*)(atb + ni * 512);
    BAR_LGKM();
    for (int kp = 0; kp < 8; ++kp) {
      G1ITER(2 * kp,     As0, As1, bA, bB);
      G1ITER(2 * kp + 1, As1, As0, bB, bA);
    }
  }
  // ---------- phase 1: t (+w0) -> R1[128][512] unswizzled ----------
#pragma unroll
  for (int ni = 0; ni < 4; ++ni) {
    const int col = w * 64 + ni * 16 + lr;
    const float b0 = w0[col];
#pragma unroll
    for (int mi = 0; mi < 8; ++mi)
#pragma unroll
      for (int r = 0; r < 4; ++r)
        R1[(mi * 16 + kg * 4 + r) * DD + col] = f2bf(acc[mi][ni][r] + b0);
  }
  BAR_LGKM();
  // ---------- phase 2: attention, 2-row batched; t -> mbar in place (swizzled) ----------
  const float scale = 0.044194173824159216f;  // 512^-0.5
  for (int rr = 0; rr < 16; rr += 2) {
    const int row0 = w * 16 + rr;
    const size_t b0 = (size_t)bm * 128 + row0;
    const short8 tv0 = *(const short8*)&R1[row0 * DD + lane * 8];
    const short8 tv1 = *(const short8*)&R1[(row0 + 1) * DD + lane * 8];
    float tf0[8], tf1[8];
#pragma unroll
    for (int i = 0; i < 8; ++i) { tf0[i] = bf2f(tv0[i]); tf1[i] = bf2f(tv1[i]); }
    int vm0 = 0, vm1 = 0;
#pragma unroll
    for (int k = 0; k < KM; ++k) {
      vm0 |= (__builtin_amdgcn_readfirstlane(mask[b0 * KM + k]) ? 1 : 0) << k;
      vm1 |= (__builtin_amdgcn_readfirstlane(mask[(b0 + 1) * KM + k]) ? 1 : 0) << k;
    }
    f32x4 ma0[KM], mc0[KM], ma1[KM], mc1[KM];
#pragma unroll
    for (int k = 0; k < KM; ++k) {
      if (vm0 & (1 << k)) {
        const f32x4* mp = (const f32x4*)(mem + (b0 * KM + k) * DD + lane * 8);
        ma0[k] = __builtin_nontemporal_load(mp);
        mc0[k] = __builtin_nontemporal_load(mp + 1);
      }
      if (vm1 & (1 << k)) {
        const f32x4* mp = (const f32x4*)(mem + ((b0 + 1) * KM + k) * DD + lane * 8);
        ma1[k] = __builtin_nontemporal_load(mp);
        mc1[k] = __builtin_nontemporal_load(mp + 1);
      }
    }
    float s0[KM], s1[KM];
#pragma unroll
    for (int k = 0; k < KM; ++k) {
      if (vm0 & (1 << k)) {
        float p = 0.f;
#pragma unroll
        for (int i = 0; i < 4; ++i) { p += tf0[i] * ma0[k][i]; p += tf0[4 + i] * mc0[k][i]; }
#pragma unroll
        for (int off = 32; off > 0; off >>= 1) p += __shfl_xor(p, off);
        s0[k] = p * scale;
      }
      if (vm1 & (1 << k)) {
        float p = 0.f;
#pragma unroll
        for (int i = 0; i < 4; ++i) { p += tf1[i] * ma1[k][i]; p += tf1[4 + i] * mc1[k][i]; }
#pragma unroll
        for (int off = 32; off > 0; off >>= 1) p += __shfl_xor(p, off);
        s1[k] = p * scale;
      }
    }
    ROW_FINISH(s0, ma0, mc0, vm0, row0)
    ROW_FINISH(s1, ma1, mc1, vm1, (row0 + 1))
  }
  BAR_LGKM();
  // ---------- phase 3: GEMM2  memO = mbar @ C  (barrier-free k-loop) ----------
  f32x4 acc2[8][4] = {};
  {
    short8 cA[4], cB[4];
#pragma unroll
    for (int ni = 0; ni < 4; ++ni) cA[ni] = *(const short8*)(ctb + ni * 512);
    for (int kp = 0; kp < 8; ++kp) {
      G2ITER(2 * kp,     cA, cB);
      G2ITER(2 * kp + 1, cB, cA);
    }
  }
  BAR_LGKM();                         // all waves' R1 reads done before overwrite
  // ---------- phase 4: memO (+d0) -> R1 unswizzled ----------
#pragma unroll
  for (int ni = 0; ni < 4; ++ni) {
    const int col = w * 64 + ni * 16 + lr;
    const float b0 = d0[col];
#pragma unroll
    for (int mi = 0; mi < 8; ++mi)
#pragma unroll
      for (int r = 0; r < 4; ++r)
        R1[(mi * 16 + kg * 4 + r) * DD + col] = f2bf(acc2[mi][ni][r] + b0);
  }
  BAR_LGKM();
  // ---------- phase 5: gate/conf/residual/LayerNorm -> out ----------
  {
    const float* wg1 = Wg + lane * 8;
    const float* wg2 = Wg + DD + lane * 8;
    f32x4 g1a = *(const f32x4*)wg1, g1b = *(const f32x4*)(wg1 + 4);
    f32x4 g2a = *(const f32x4*)wg2, g2b = *(const f32x4*)(wg2 + 4);
    f32x4 la = *(const f32x4*)(lng + lane * 8), lb4 = *(const f32x4*)(lng + lane * 8 + 4);
    f32x4 ba = *(const f32x4*)(lnb + lane * 8), bb4 = *(const f32x4*)(lnb + lane * 8 + 4);
    const float bgs = bgp[0];
    for (int rr = 0; rr < 16; ++rr) {
      const int row = w * 16 + rr;
      const size_t b = (size_t)bm * 128 + row;
      const float* qp = q + b * DD + lane * 8;
      f32x4 q0 = *(const f32x4*)qp;
      f32x4 q1 = *(const f32x4*)(qp + 4);
      float qf[8] = {q0[0],q0[1],q0[2],q0[3],q1[0],q1[1],q1[2],q1[3]};
      const short8 mv = *(const short8*)&R1[row * DD + lane * 8];
      float mf[8];
#pragma unroll
      for (int i = 0; i < 8; ++i) mf[i] = bf2f(mv[i]);
      float gp = qf[0]*g1a[0]+qf[1]*g1a[1]+qf[2]*g1a[2]+qf[3]*g1a[3]
               + qf[4]*g1b[0]+qf[5]*g1b[1]+qf[6]*g1b[2]+qf[7]*g1b[3]
               + mf[0]*g2a[0]+mf[1]*g2a[1]+mf[2]*g2a[2]+mf[3]*g2a[3]
               + mf[4]*g2b[0]+mf[5]*g2b[1]+mf[6]*g2b[2]+mf[7]*g2b[3];
#pragma unroll
      for (int off = 32; off > 0; off >>= 1) gp += __shfl_xor(gp, off);
      const float gate = 1.f / (1.f + __expf(-(gp + bgs)));
      float ms = sims[b * KM];
#pragma unroll
      for (int k = 1; k < KM; ++k) ms = fmaxf(ms, sims[b * KM + k]);
      const float conf = 1.f / (1.f + __expf(-(ms - 0.7f)));
      const float gc = gate * conf;
      float o[8];
      float s1 = 0.f, s2 = 0.f;
#pragma unroll
      for (int i = 0; i < 8; ++i) {
        o[i] = qf[i] + gc * mf[i];
        s1 += o[i];
        s2 += o[i] * o[i];
      }
#pragma unroll
      for (int off = 32; off > 0; off >>= 1) { s1 += __shfl_xor(s1, off); s2 += __shfl_xor(s2, off); }
      const float mu = s1 * (1.f / 512.f);
      const float var = s2 * (1.f / 512.f) - mu * mu;
      const float rs = rsqrtf(var + 1e-5f);
      f32x4 r0, r1;
#pragma unroll
      for (int i = 0; i < 4; ++i) r0[i] = (o[i] - mu) * rs * la[i] + ba[i];
#pragma unroll
      for (int i = 0; i < 4; ++i) r1[i] = (o[4 + i] - mu) * rs * lb4[i] + bb4[i];
      float* op = outp + b * DD + lane * 8;
      __builtin_nontemporal_store(r0, (f32x4*)op);
      __builtin_nontemporal_store(r1, (f32x4*)(op + 4));
    }
  }
}

extern "C" void kernel_launch(void* const* d_in, const int* in_sizes, int n_in,
                              void* d_out, int out_size, void* d_ws, size_t ws_size,
                              hipStream_t stream) {
  const float* query = (const float*)d_in[0];
  const float* mem   = (const float*)d_in[1];
  const float* sims  = (const float*)d_in[2];
  const int*   mask  = (const int*)d_in[3];
  const float* Wq = (const float*)d_in[4];
  const float* bq = (const float*)d_in[5];
  const float* Wk = (const float*)d_in[6];
  // d_in[7] = bk: irrelevant (per-row constant on scores; softmax shift-invariant)
  const float* Wv = (const float*)d_in[8];
  const float* bv = (const float*)d_in[9];
  const float* Wo = (const float*)d_in[10];
  const float* bo = (const float*)d_in[11];
  const float* Wg = (const float*)d_in[12];
  const float* bg = (const float*)d_in[13];
  const float* ln_g = (const float*)d_in[14];
  const float* ln_b = (const float*)d_in[15];
  float* out = (float*)d_out;

  char* ws = (char*)d_ws;
  short* AtP = (short*)ws;                              // 512 KB packed [16][512][32] bf16
  short* CtP = AtP + (size_t)DD * DD;                   // 512 KB packed
  float* w0 = (float*)(CtP + (size_t)DD * DD);          // 2 KB
  float* d0 = w0 + DD;                                  // 2 KB

  prepG<<<dim3(130), dim3(512), 0, stream>>>(Wq, bq, Wk, Wv, Wo, bo, bv, AtP, CtP, w0, d0);
  mk<<<dim3(B_ROWS / 128), dim3(512), 0, stream>>>(query, AtP, w0, mem, mask,
                                                   CtP, d0, sims, Wg, bg, ln_g, ln_b, out);
}